// Round 17
// baseline (118.028 us; speedup 1.0000x reference)
//
#include <hip/hip_runtime.h>
#include <hip/hip_bf16.h>
#include <stdint.h>

#define BB   2048
#define DD   150
#define DKK  64

static constexpr int EXPERT_W  = 1774;        // 5*150 + 10*64 + 256 + 128
static constexpr int X_OFF     = 1390;
static constexpr int W_OFF     = 1646;
static constexpr int EXPERT_SZ = BB * EXPERT_W;
static constexpr int OH_BASE   = EXPERT_SZ;
static constexpr int FM_BASE   = OH_BASE + BB * 3;

// ---- workspace layout (bytes) ----
// WtX: 1500 tiles (T = jj*300 + i) of 16384 B.
//      tile = [blk 0..15][ksub 0..3][nloc 0..15][e 0..7] bf16
//      value = W256[(i*150 + jj*32 + ksub*8 + e)][blk*16+nloc], 0 if j>=150
// WtW: 256 tiles (T = jj*128 + i) of 8192 B, same layout (blk 0..7).
static constexpr size_t WTX_OFF = 0;               // 24,576,000 B
static constexpr size_t WTW_OFF = 24576000;        //  2,097,152 B
static constexpr size_t WSX_OFF = 26673152;        // bf16 [32][2048][256] = 33,554,432
static constexpr size_t WSW_OFF = 60227584;        // bf16 [16][2048][128] =  8,388,608
static constexpr size_t WS_NEED = 68616192;

typedef __attribute__((ext_vector_type(8))) short bf16x8;
typedef __attribute__((ext_vector_type(4))) float f32x4;

union APack { int d[4]; bf16x8 v; };

__device__ __forceinline__ int cvtpk_bf16(float a, float b) {
  int r; asm("v_cvt_pk_bf16_f32 %0, %1, %2" : "=v"(r) : "v"(a), "v"(b)); return r;
}
__device__ __forceinline__ f32x4 mfma16(bf16x8 a, bf16x8 b, f32x4 c) {
  return __builtin_amdgcn_mfma_f32_16x16x32_bf16(a, b, c, 0, 0, 0);
}
__device__ __forceinline__ void gload16(const void* g, void* l) {
  __builtin_amdgcn_global_load_lds(
      (__attribute__((address_space(1))) void*)(g),
      (__attribute__((address_space(3))) void*)(l), 16, 0, 0);
}
__device__ __forceinline__ float bfu2f(uint32_t u) { return __uint_as_float(u << 16); }

// ---------------------------------------------------------------------------
// Prep kernel (proven): gather (0..2047) + tile_pack_x (2048..3547)
// + tile_pack_w (3548..3803).
// ---------------------------------------------------------------------------
__global__ __launch_bounds__(256) void prep_kernel(
    const int* __restrict__ inputs, const int* __restrict__ shifts,
    const float* __restrict__ Wuf, const float* __restrict__ Wfu,
    const float* __restrict__ Wua, const float* __restrict__ Wau,
    const float* __restrict__ Wfe,
    const float* __restrict__ Wut, const float* __restrict__ Wuk1, const float* __restrict__ Wuk2,
    const float* __restrict__ Wft, const float* __restrict__ Wfk1, const float* __restrict__ Wfk2,
    const float* __restrict__ Wufd, const float* __restrict__ Wfud,
    const float* __restrict__ Wuad, const float* __restrict__ Waud,
    const float* __restrict__ W256, __hip_bfloat16* __restrict__ WtX,
    const float* __restrict__ W128, __hip_bfloat16* __restrict__ WtW,
    float* __restrict__ out)
{
  const int blk = blockIdx.x;
  const int t = threadIdx.x;

  if (blk < 2048) {                      // ---- gather ----
    const int b = blk;
    const int u = inputs[b*3 + 0];
    const int f = inputs[b*3 + 1];
    const int a = inputs[b*3 + 2];
    float* row = out + b * EXPERT_W;
    float* fm  = out + FM_BASE;

    for (int c = t; c < DD; c += 256) {
        float ufe = Wuf[u*DD + c];
        float uae = Wua[u*DD + c];
        float fue = Wfu[f*DD + c];
        float fee = Wfe[f*DD + c];
        float aue = Wau[a*DD + c];
        row[0    + c] = ufe;
        row[150  + c] = uae;
        row[620  + c] = fue;
        row[898  + c] = fee;
        row[1176 + c] = aue;
        fm[0*BB*DD + b*DD + c] = ufe;
        fm[1*BB*DD + b*DD + c] = uae;
        fm[2*BB*DD + b*DD + c] = fue;
        fm[3*BB*DD + b*DD + c] = aue;
    }
    for (int c = t; c < DKK; c += 256) {
        row[300  + c] = Wut [u*DKK + c];
        row[364  + c] = Wuk1[u*DKK + c];
        row[428  + c] = Wuk2[u*DKK + c];
        row[492  + c] = Wufd[u*DKK + c];
        row[556  + c] = Wuad[u*DKK + c];
        row[770  + c] = Wft [f*DKK + c];
        row[834  + c] = Wfk1[f*DKK + c];
        row[1048 + c] = Wfk2[f*DKK + c];
        row[1112 + c] = Wfud[f*DKK + c];
        row[1326 + c] = Waud[a*DKK + c];
    }
    if (t < 3) out[OH_BASE + b*3 + t] = (float)(inputs[b*3 + t] + shifts[t]);

  } else if (blk < 2048 + 1500) {        // ---- tile_pack_x ----
    const int T  = blk - 2048;
    const int jj = T / 300;
    const int i  = T - jj*300;
    float v[32];
    const float* src = W256 + ((size_t)i*150 + jj*32)*256 + t;
    #pragma unroll
    for (int jl = 0; jl < 32; ++jl) {
      int j = jj*32 + jl;
      v[jl] = (j < 150) ? src[(size_t)jl*256] : 0.f;
    }
    const int b16 = t >> 4, nloc = t & 15;
    char* dst = (char*)WtX + (size_t)T*16384 + (size_t)(b16*512 + nloc*8)*2;
    #pragma unroll
    for (int ksub = 0; ksub < 4; ++ksub) {
      int pk0 = cvtpk_bf16(v[ksub*8+0], v[ksub*8+1]);
      int pk1 = cvtpk_bf16(v[ksub*8+2], v[ksub*8+3]);
      int pk2 = cvtpk_bf16(v[ksub*8+4], v[ksub*8+5]);
      int pk3 = cvtpk_bf16(v[ksub*8+6], v[ksub*8+7]);
      *(int4*)(dst + (size_t)ksub*256) = make_int4(pk0, pk1, pk2, pk3);
    }

  } else {                               // ---- tile_pack_w ----
    if (t >= 128) return;
    const int T  = blk - 3548;
    const int jj = T >> 7;
    const int i  = T & 127;
    float v[32];
    const float* src = W128 + ((size_t)i*64 + jj*32)*128 + t;
    #pragma unroll
    for (int jl = 0; jl < 32; ++jl) v[jl] = src[(size_t)jl*128];
    const int b16 = t >> 4, nloc = t & 15;
    char* dst = (char*)WtW + (size_t)T*8192 + (size_t)(b16*512 + nloc*8)*2;
    #pragma unroll
    for (int ksub = 0; ksub < 4; ++ksub) {
      int pk0 = cvtpk_bf16(v[ksub*8+0], v[ksub*8+1]);
      int pk1 = cvtpk_bf16(v[ksub*8+2], v[ksub*8+3]);
      int pk2 = cvtpk_bf16(v[ksub*8+4], v[ksub*8+5]);
      int pk3 = cvtpk_bf16(v[ksub*8+6], v[ksub*8+7]);
      *(int4*)(dst + (size_t)ksub*256) = make_int4(pk0, pk1, pk2, pk3);
    }
  }
}

// ---------------------------------------------------------------------------
// xuser MFMA: SPLITK=32 -> grid 1024 = 16mb x 32s x 2h -> 4 blocks/CU
// (LDS 38,912 B: xlds stride 12 + 4 x 8KB ring). Inner loop = r16 (proven).
// ---------------------------------------------------------------------------
static constexpr int XST = 12;     // xlds stride (cnt <= 10)

__global__ __launch_bounds__(512, 4) void xuser_mfma(
    const int* __restrict__ inputs,
    const float* __restrict__ Wuf, const float* __restrict__ Wua,
    const float* __restrict__ Wfu, const float* __restrict__ Wau,
    const __hip_bfloat16* __restrict__ WtXt, __hip_bfloat16* __restrict__ wsX)
{
  __shared__ float xlds[128*XST];                           // 6144 B
  __shared__ __align__(16) __hip_bfloat16 blds[4][4096];    // 4 x 8192 B ring

  const int bid = blockIdx.x;
  const int h  = bid & 1;
  const int s  = (bid >> 1) & 31;                  // 0..31
  const int mb = bid >> 6;                         // 0..15
  const int b0 = mb * 128;
  const bool upper = s >= 16;
  const int sl  = upper ? s - 16 : s;
  const int i0l = (sl * 150) >> 4;
  const int cnt = (((sl + 1) * 150) >> 4) - i0l;   // 9 or 10
  const int ig0 = i0l + (upper ? 150 : 0);
  const int tid = threadIdx.x;

  const float* X = upper ? Wua : Wuf;
  const float* Y = upper ? Wau : Wfu;
  const int yoff = upper ? 2 : 1;

  for (int k = tid; k < 128*XST; k += 512) {
    int r = k / XST, ii = k - r*XST;
    float v = 0.f;
    if (ii < cnt) v = X[(size_t)inputs[(b0+r)*3]*150 + i0l + ii];
    xlds[k] = v;
  }

  const int lane = tid & 63;
  const int w  = tid >> 6;
  const int mg = w >> 1;        // 0..3 (32 rows each)
  const int ng = w & 1;         // 0..1 (64 cols each)
  const int lr = lane & 15;
  const int g  = lane >> 4;
  const unsigned wdst = (unsigned)(tid & ~63) * 16;

  int yid[2];
  #pragma unroll
  for (int mf = 0; mf < 2; ++mf)
    yid[mf] = inputs[(size_t)(b0 + mg*32 + mf*16 + lr)*3 + yoff];

  const char* wtb = (const char*)WtXt + (size_t)h*8192;

  int jjs = 0, iis = 0;
  auto stage1 = [&](int slot) {
    const char* sp = wtb + (size_t)(jjs*300 + ig0 + iis)*16384 + (size_t)tid*16;
    gload16(sp, (char*)&blds[slot][0] + wdst);
    if (iis + 1 < cnt) ++iis;
    else if (jjs + 1 < 5) { iis = 0; ++jjs; }
  };

  f32x4 acc[2][4];
  #pragma unroll
  for (int i = 0; i < 2; ++i)
    #pragma unroll
    for (int j = 0; j < 4; ++j) acc[i][j] = (f32x4){0.f,0.f,0.f,0.f};

  const int NW = 5 * cnt;       // cells (45 or 50)

  stage1(0); stage1(1); stage1(2);      // depth-3 prefetch

  int jjc = 0, iic = 0;
  int yjj = -1;
  float yreg[2][8];

  for (int wi = 0; wi < NW; ++wi) {
    const int ahead = NW - 1 - wi;
    if (ahead >= 2)      asm volatile("s_waitcnt vmcnt(2)" ::: "memory");
    else if (ahead == 1) asm volatile("s_waitcnt vmcnt(1)" ::: "memory");
    else                 asm volatile("s_waitcnt vmcnt(0)" ::: "memory");
    __builtin_amdgcn_s_barrier();

    if (wi + 3 < NW) stage1((wi + 3) & 3);
    __builtin_amdgcn_sched_barrier(0);
    __builtin_amdgcn_s_setprio(1);

    if (jjc != yjj) {
      yjj = jjc;
      const int jb = jjc*32 + g*8;
      #pragma unroll
      for (int mf = 0; mf < 2; ++mf) {
        const float* yp = Y + (size_t)yid[mf]*150;
        if (jb + 8 <= 150) {
          #pragma unroll
          for (int hh = 0; hh < 4; ++hh) {
            float2 vv = *(const float2*)(yp + jb + 2*hh);
            yreg[mf][2*hh]   = vv.x;
            yreg[mf][2*hh+1] = vv.y;
          }
        } else {
          #pragma unroll
          for (int e = 0; e < 8; ++e)
            yreg[mf][e] = (jb + e < 150) ? yp[jb + e] : 0.f;
        }
      }
    }
    const __hip_bfloat16* bb = &blds[wi & 3][0];
    bf16x8 bv[4];
    #pragma unroll
    for (int nf = 0; nf < 4; ++nf)
      bv[nf] = *(const bf16x8*)(bb + (ng*4 + nf)*512 + g*128 + lr*8);
    APack a[2];
    #pragma unroll
    for (int mf = 0; mf < 2; ++mf) {
      const float xv = xlds[(mg*32 + mf*16 + lr)*XST + iic];
      #pragma unroll
      for (int e = 0; e < 4; ++e)
        a[mf].d[e] = cvtpk_bf16(xv*yreg[mf][2*e], xv*yreg[mf][2*e+1]);
    }
    #pragma unroll
    for (int mf = 0; mf < 2; ++mf)
      #pragma unroll
      for (int nf = 0; nf < 4; ++nf)
        acc[mf][nf] = mfma16(a[mf].v, bv[nf], acc[mf][nf]);

    __builtin_amdgcn_s_setprio(0);
    ++iic; if (iic >= cnt) { iic = 0; ++jjc; }
  }

  __hip_bfloat16* wp = wsX + ((size_t)s*2048 + b0)*256;
  #pragma unroll
  for (int mf = 0; mf < 2; ++mf) {
    #pragma unroll
    for (int nf = 0; nf < 4; ++nf) {
      int rb  = mg*32 + mf*16 + g*4;
      int col = h*128 + ng*64 + nf*16 + lr;
      f32x4 v = acc[mf][nf];
      #pragma unroll
      for (int e = 0; e < 4; ++e)
        wp[(size_t)(rb+e)*256 + col] = __float2bfloat16(v[e]);
    }
  }
}

// ---------------------------------------------------------------------------
// wuser MFMA (proven): counted-vmcnt pipeline, bf16 partials.
// grid 256 = 16 mb x 16 s. 8 waves (4 mg x 2 ng); wave = 2 mf x 4 nf.
// ---------------------------------------------------------------------------
__global__ __launch_bounds__(512, 4) void wuser_mfma(
    const int* __restrict__ inputs,
    const float* __restrict__ Wufd, const float* __restrict__ Wuad,
    const float* __restrict__ Wfud, const float* __restrict__ Waud,
    const __hip_bfloat16* __restrict__ WtWt, __hip_bfloat16* __restrict__ wsW)
{
  __shared__ float xlds[128*8];                           // 4 KB
  __shared__ __align__(16) __hip_bfloat16 blds[2][8192];  // 2 x 16 KB

  const int mb = blockIdx.x >> 4;
  const int s  = blockIdx.x & 15;
  const int b0 = mb * 128;
  const bool upper = s >= 8;
  const int i0l = (s & 7) * 8;
  const int ig0 = i0l + (upper ? 64 : 0);
  const int tid = threadIdx.x;

  const float* X = upper ? Wuad : Wufd;
  const float* Y = upper ? Waud : Wfud;
  const int yoff = upper ? 2 : 1;

  for (int k = tid; k < 128*8; k += 512) {
    int r = k >> 3, ii = k & 7;
    xlds[k] = X[(size_t)inputs[(size_t)(b0+r)*3]*64 + i0l + ii];
  }

  const int lane = tid & 63;
  const int w  = tid >> 6;
  const int mg = w >> 1;
  const int ng = w & 1;
  const int lr = lane & 15;
  const int g  = lane >> 4;
  const unsigned wdst = (unsigned)(tid & ~63) * 16;

  int yid[2];
  #pragma unroll
  for (int mf = 0; mf < 2; ++mf)
    yid[mf] = inputs[(size_t)(b0 + mg*32 + mf*16 + lr)*3 + yoff];

  const char* wtb = (const char*)WtWt;

  auto stageT = [&](int bufi, int T) {
    const char* sp = wtb + (size_t)T*8192 + (size_t)tid*16;
    char* dp = (char*)&blds[bufi][0] + wdst;
    gload16(sp,        dp);
    gload16(sp + 8192, dp + 8192);
  };

  f32x4 acc[2][4];
  #pragma unroll
  for (int i = 0; i < 2; ++i)
    #pragma unroll
    for (int j = 0; j < 4; ++j) acc[i][j] = (f32x4){0.f,0.f,0.f,0.f};

  stageT(0, ig0);
  stageT(1, ig0 + 2);

  int jjc = 0, iic = 0;
  int jjs = 0, iis = 4;
  int yjj = -1;
  float yreg[2][8];

  for (int p = 0; p < 8; ++p) {
    if (jjc != yjj) {
      yjj = jjc;
      const int jb = jjc*32 + g*8;
      #pragma unroll
      for (int mf = 0; mf < 2; ++mf) {
        const float* yp = Y + (size_t)yid[mf]*64 + jb;
        #pragma unroll
        for (int hh = 0; hh < 2; ++hh) {
          float4 v = *(const float4*)(yp + hh*4);
          yreg[mf][hh*4]   = v.x;
          yreg[mf][hh*4+1] = v.y;
          yreg[mf][hh*4+2] = v.z;
          yreg[mf][hh*4+3] = v.w;
        }
      }
    }
    if (p + 1 < 8) asm volatile("s_waitcnt vmcnt(2)" ::: "memory");
    else           asm volatile("s_waitcnt vmcnt(0)" ::: "memory");
    __builtin_amdgcn_s_barrier();
    __builtin_amdgcn_sched_barrier(0);

    const int buf = p & 1;
    #pragma unroll
    for (int sc = 0; sc < 2; ++sc) {
      const __hip_bfloat16* bb = &blds[buf][sc*4096];
      bf16x8 bv[4];
      #pragma unroll
      for (int nf = 0; nf < 4; ++nf)
        bv[nf] = *(const bf16x8*)(bb + (ng*4 + nf)*512 + g*128 + lr*8);
      APack a[2];
      #pragma unroll
      for (int mf = 0; mf < 2; ++mf) {
        float xv = xlds[(mg*32 + mf*16 + lr)*8 + iic + sc];
        #pragma unroll
        for (int e = 0; e < 4; ++e)
          a[mf].d[e] = cvtpk_bf16(xv*yreg[mf][2*e], xv*yreg[mf][2*e+1]);
      }
      #pragma unroll
      for (int mf = 0; mf < 2; ++mf)
        #pragma unroll
        for (int nf = 0; nf < 4; ++nf)
          acc[mf][nf] = mfma16(a[mf].v, bv[nf], acc[mf][nf]);
    }

    __builtin_amdgcn_s_barrier();
    if (p + 2 < 8) stageT(buf, jjs*128 + ig0 + iis);

    iic += 2; if (iic >= 8) { iic = 0; ++jjc; }
    iis += 2; if (iis >= 8) { iis = 0; ++jjs; }
  }

  __hip_bfloat16* wp = wsW + ((size_t)s*2048 + b0)*128;
  #pragma unroll
  for (int mf = 0; mf < 2; ++mf) {
    #pragma unroll
    for (int nf = 0; nf < 4; ++nf) {
      int rb  = mg*32 + mf*16 + g*4;
      int col = ng*64 + nf*16 + lr;
      f32x4 v = acc[mf][nf];
      #pragma unroll
      for (int e = 0; e < 4; ++e)
        wp[(size_t)(rb+e)*128 + col] = __float2bfloat16(v[e]);
    }
  }
}

// ---------------------------------------------------------------------------
// Epilogue: sum bf16 partials (32 for X, 16 for W) + bias + relu.
// ---------------------------------------------------------------------------
__global__ __launch_bounds__(256) void epilogue_kernel(
    const __hip_bfloat16* __restrict__ wsX, const __hip_bfloat16* __restrict__ wsW,
    const float* __restrict__ b256, const float* __restrict__ b128,
    float* __restrict__ out)
{
  int idx = blockIdx.x*256 + threadIdx.x;
  if (idx >= BB*192) return;
  int b = idx / 192, c2 = idx - b*192;
  if (c2 < 128) {
    int c = c2*2;
    float a0 = b256[c], a1 = b256[c+1];
    #pragma unroll
    for (int k = 0; k < 32; ++k) {
      uint32_t u = *(const uint32_t*)(wsX + ((size_t)k*BB + b)*256 + c);
      a0 += bfu2f(u);
      a1 += __uint_as_float(u & 0xffff0000u);
    }
    float2 r = make_float2(a0 > 0.f ? a0 : 0.f, a1 > 0.f ? a1 : 0.f);
    *(float2*)(out + (size_t)b*EXPERT_W + X_OFF + c) = r;
  } else {
    int cc = (c2 - 128)*2;
    float a0 = b128[cc], a1 = b128[cc+1];
    #pragma unroll
    for (int k = 0; k < 16; ++k) {
      uint32_t u = *(const uint32_t*)(wsW + ((size_t)k*BB + b)*128 + cc);
      a0 += bfu2f(u);
      a1 += __uint_as_float(u & 0xffff0000u);
    }
    float2 r = make_float2(a0 > 0.f ? a0 : 0.f, a1 > 0.f ? a1 : 0.f);
    *(float2*)(out + (size_t)b*EXPERT_W + W_OFF + cc) = r;
  }
}

// ---------------------------------------------------------------------------
// Fallback path (round-2, verified-passing) used if ws too small.
// ---------------------------------------------------------------------------
__global__ __launch_bounds__(256) void gather_kernel(
    const int* __restrict__ inputs, const int* __restrict__ shifts,
    const float* __restrict__ Wuf, const float* __restrict__ Wfu,
    const float* __restrict__ Wua, const float* __restrict__ Wau,
    const float* __restrict__ Wfe,
    const float* __restrict__ Wut, const float* __restrict__ Wuk1, const float* __restrict__ Wuk2,
    const float* __restrict__ Wft, const float* __restrict__ Wfk1, const float* __restrict__ Wfk2,
    const float* __restrict__ Wufd, const float* __restrict__ Wfud,
    const float* __restrict__ Wuad, const float* __restrict__ Waud,
    float* __restrict__ out)
{
    const int b = blockIdx.x;
    const int u = inputs[b*3 + 0];
    const int f = inputs[b*3 + 1];
    const int a = inputs[b*3 + 2];
    float* row = out + b * EXPERT_W;
    float* fm  = out + FM_BASE;
    const int t = threadIdx.x;

    for (int c = t; c < DD; c += 256) {
        float ufe = Wuf[u*DD + c];
        float uae = Wua[u*DD + c];
        float fue = Wfu[f*DD + c];
        float fee = Wfe[f*DD + c];
        float aue = Wau[a*DD + c];
        row[0    + c] = ufe;
        row[150  + c] = uae;
        row[620  + c] = fue;
        row[898  + c] = fee;
        row[1176 + c] = aue;
        fm[0*BB*DD + b*DD + c] = ufe;
        fm[1*BB*DD + b*DD + c] = uae;
        fm[2*BB*DD + b*DD + c] = fue;
        fm[3*BB*DD + b*DD + c] = aue;
    }
    for (int c = t; c < DKK; c += 256) {
        row[300  + c] = Wut [u*DKK + c];
        row[364  + c] = Wuk1[u*DKK + c];
        row[428  + c] = Wuk2[u*DKK + c];
        row[492  + c] = Wufd[u*DKK + c];
        row[556  + c] = Wuad[u*DKK + c];
        row[770  + c] = Wft [f*DKK + c];
        row[834  + c] = Wfk1[f*DKK + c];
        row[1048 + c] = Wfk2[f*DKK + c];
        row[1112 + c] = Wfud[f*DKK + c];
        row[1326 + c] = Waud[a*DKK + c];
    }
    if (t < 3) {
        out[OH_BASE + b*3 + t] = (float)(inputs[b*3 + t] + shifts[t]);
    }
}

static constexpr int NPAIR_X = 300 * 150;
static constexpr int CHX     = 128;

__global__ __launch_bounds__(256) void xuser_kernel(
    const int* __restrict__ inputs,
    const float* __restrict__ Wuf, const float* __restrict__ Wua,
    const float* __restrict__ Wfu, const float* __restrict__ Wau,
    const float* __restrict__ W256, const float* __restrict__ b256,
    float* __restrict__ out)
{
    __shared__ float xs[16][308];
    __shared__ float ys[16][308];
    __shared__ float xy[CHX][16];
    const int half = blockIdx.x & 1;
    const int bg   = blockIdx.x >> 1;
    const int b0   = bg * 16;
    const int t    = threadIdx.x;
    const int bl   = t & 15;
    const int kg   = t >> 4;
    const int kbase = half * 128 + kg * 8;
    for (int idx = t; idx < 16 * DD; idx += 256) {
        int bb = idx / DD;
        int c  = idx - bb * DD;
        int u = inputs[(b0+bb)*3 + 0];
        int f = inputs[(b0+bb)*3 + 1];
        int a = inputs[(b0+bb)*3 + 2];
        xs[bb][c]       = Wuf[u*DD + c];
        xs[bb][150 + c] = Wua[u*DD + c];
        ys[bb][c]       = Wfu[f*DD + c];
        ys[bb][150 + c] = Wau[a*DD + c];
    }
    float acc[8] = {0,0,0,0,0,0,0,0};
    for (int base = 0; base < NPAIR_X; base += CHX) {
        __syncthreads();
        #pragma unroll
        for (int r = 0; r < (CHX*16)/256; ++r) {
            int idx = t + r * 256;
            int pl  = idx >> 4;
            int bb  = idx & 15;
            int p   = base + pl;
            if (p < NPAIR_X) {
                int i = p / 150;
                int j = p - i * 150;
                xy[pl][bb] = xs[bb][i] * ys[bb][(i >= 150 ? 150 : 0) + j];
            }
        }
        __syncthreads();
        const int lim = min(CHX, NPAIR_X - base);
        const float* wp = W256 + base * 256 + kbase;
        for (int pl = 0; pl < lim; ++pl) {
            float sv = xy[pl][bl];
            const float4* w4 = (const float4*)(wp + pl * 256);
            float4 w0 = w4[0], w1 = w4[1];
            acc[0] = fmaf(sv, w0.x, acc[0]); acc[1] = fmaf(sv, w0.y, acc[1]);
            acc[2] = fmaf(sv, w0.z, acc[2]); acc[3] = fmaf(sv, w0.w, acc[3]);
            acc[4] = fmaf(sv, w1.x, acc[4]); acc[5] = fmaf(sv, w1.y, acc[5]);
            acc[6] = fmaf(sv, w1.z, acc[6]); acc[7] = fmaf(sv, w1.w, acc[7]);
        }
    }
    const int rowbase = (b0 + bl) * EXPERT_W + X_OFF;
    #pragma unroll
    for (int m = 0; m < 8; ++m) {
        float v = acc[m] + b256[kbase + m];
        out[rowbase + kbase + m] = (v > 0.f ? v : 0.f);
    }
}

static constexpr int NPAIR_W = 128 * 64;
static constexpr int CHW     = 256;

__global__ __launch_bounds__(256) void wuser_kernel(
    const int* __restrict__ inputs,
    const float* __restrict__ Wufd, const float* __restrict__ Wuad,
    const float* __restrict__ Wfud, const float* __restrict__ Waud,
    const float* __restrict__ W128, const float* __restrict__ b128,
    float* __restrict__ out)
{
    __shared__ float xs[8][132];
    __shared__ float ys[8][132];
    __shared__ float xy[CHW][8];
    const int bg = blockIdx.x;
    const int b0 = bg * 8;
    const int t  = threadIdx.x;
    const int bl = t & 7;
    const int kg = t >> 3;
    const int kbase = kg * 4;
    for (int idx = t; idx < 8 * DKK; idx += 256) {
        int bb = idx >> 6;
        int c  = idx & 63;
        int u = inputs[(b0+bb)*3 + 0];
        int f = inputs[(b0+bb)*3 + 1];
        int a = inputs[(b0+bb)*3 + 2];
        xs[bb][c]      = Wufd[u*DKK + c];
        xs[bb][64 + c] = Wuad[u*DKK + c];
        ys[bb][c]      = Wfud[f*DKK + c];
        ys[bb][64 + c] = Waud[a*DKK + c];
    }
    float acc[4] = {0,0,0,0};
    for (int base = 0; base < NPAIR_W; base += CHW) {
        __syncthreads();
        #pragma unroll
        for (int r = 0; r < (CHW*8)/256; ++r) {
            int idx = t + r * 256;
            int pl  = idx >> 3;
            int bb  = idx & 7;
            int p   = base + pl;
            int i = p >> 6;
            int j = p & 63;
            xy[pl][bb] = xs[bb][i] * ys[bb][(i >= 64 ? 64 : 0) + j];
        }
        __syncthreads();
        const float* wp = W128 + base * 128 + kbase;
        for (int pl = 0; pl < CHW; ++pl) {
            float sv = xy[pl][bl];
            float4 wv = *(const float4*)(wp + pl * 128);
            acc[0] = fmaf(sv, wv.x, acc[0]); acc[1] = fmaf(sv, wv.y, acc[1]);
            acc[2] = fmaf(sv, wv.z, acc[2]); acc[3] = fmaf(sv, wv.w, acc[3]);
        }
    }
    const int rowbase = (b0 + bl) * EXPERT_W + W_OFF;
    #pragma unroll
    for (int m = 0; m < 4; ++m) {
        float v = acc[m] + b128[kbase + m];
        out[rowbase + kbase + m] = (v > 0.f ? v : 0.f);
    }
}

// ---------------------------------------------------------------------------
extern "C" void kernel_launch(void* const* d_in, const int* in_sizes, int n_in,
                              void* d_out, int out_size, void* d_ws, size_t ws_size,
                              hipStream_t stream)
{
    const int*   inputs = (const int*)  d_in[0];
    const int*   shifts = (const int*)  d_in[1];
    const float* Wuf    = (const float*)d_in[2];
    const float* Wfu    = (const float*)d_in[3];
    const float* Wua    = (const float*)d_in[4];
    const float* Wau    = (const float*)d_in[5];
    const float* Wfe    = (const float*)d_in[6];
    const float* Wut    = (const float*)d_in[7];
    const float* Wuk1   = (const float*)d_in[8];
    const float* Wuk2   = (const float*)d_in[9];
    const float* Wft    = (const float*)d_in[10];
    const float* Wfk1   = (const float*)d_in[11];
    const float* Wfk2   = (const float*)d_in[12];
    const float* Wufd   = (const float*)d_in[13];
    const float* Wfud   = (const float*)d_in[14];
    const float* Wuad   = (const float*)d_in[15];
    const float* Waud   = (const float*)d_in[16];
    const float* W256   = (const float*)d_in[17];
    const float* b256   = (const float*)d_in[18];
    const float* W128   = (const float*)d_in[19];
    const float* b128   = (const float*)d_in[20];

    float* out = (float*)d_out;

    if (ws_size >= WS_NEED) {
        char* ws = (char*)d_ws;
        __hip_bfloat16* WtX = (__hip_bfloat16*)(ws + WTX_OFF);
        __hip_bfloat16* WtW = (__hip_bfloat16*)(ws + WTW_OFF);
        __hip_bfloat16* wsX = (__hip_bfloat16*)(ws + WSX_OFF);
        __hip_bfloat16* wsW = (__hip_bfloat16*)(ws + WSW_OFF);

        prep_kernel<<<3804, 256, 0, stream>>>(inputs, shifts,
            Wuf, Wfu, Wua, Wau, Wfe, Wut, Wuk1, Wuk2, Wft, Wfk1, Wfk2,
            Wufd, Wfud, Wuad, Waud, W256, WtX, W128, WtW, out);

        xuser_mfma<<<1024, 512, 0, stream>>>(inputs, Wuf, Wua, Wfu, Wau, WtX, wsX);
        wuser_mfma<<<256, 512, 0, stream>>>(inputs, Wufd, Wuad, Wfud, Waud, WtW, wsW);

        epilogue_kernel<<<(BB*192 + 255)/256, 256, 0, stream>>>(wsX, wsW, b256, b128, out);
    } else {
        gather_kernel<<<BB, 256, 0, stream>>>(inputs, shifts,
            Wuf, Wfu, Wua, Wau, Wfe, Wut, Wuk1, Wuk2, Wft, Wfk1, Wfk2,
            Wufd, Wfud, Wuad, Waud, out);
        xuser_kernel<<<256, 256, 0, stream>>>(inputs, Wuf, Wua, Wfu, Wau, W256, b256, out);
        wuser_kernel<<<256, 256, 0, stream>>>(inputs, Wufd, Wuad, Wfud, Waud, W128, b128, out);
    }
}

// Round 18
// 95.522 us; speedup vs baseline: 1.2356x; 1.2356x over previous
//
#include <hip/hip_runtime.h>
#include <hip/hip_bf16.h>
#include <stdint.h>

#define BB   2048
#define DD   150
#define DKK  64

static constexpr int EXPERT_W  = 1774;        // 5*150 + 10*64 + 256 + 128
static constexpr int X_OFF     = 1390;
static constexpr int W_OFF     = 1646;
static constexpr int EXPERT_SZ = BB * EXPERT_W;
static constexpr int OH_BASE   = EXPERT_SZ;
static constexpr int FM_BASE   = OH_BASE + BB * 3;

// ---- workspace layout (bytes) ----
// WtX: 1500 tiles (T = jj*300 + i) of 16384 B.
//      tile = [blk 0..15][ksub 0..3][nloc 0..15][e 0..7] bf16
//      value = W256[(i*150 + jj*32 + ksub*8 + e)][blk*16+nloc], 0 if j>=150
// WtW: 256 tiles (T = jj*128 + i) of 8192 B, same layout (blk 0..7).
static constexpr size_t WTX_OFF = 0;               // 24,576,000 B
static constexpr size_t WTW_OFF = 24576000;        //  2,097,152 B
static constexpr size_t WSX_OFF = 26673152;        // bf16 [16][2048][256]
static constexpr size_t WSW_OFF = 43450368;        // bf16 [16][2048][128]
static constexpr size_t WS_NEED = 51838976;

typedef __attribute__((ext_vector_type(8))) short bf16x8;
typedef __attribute__((ext_vector_type(4))) float f32x4;

union APack { int d[4]; bf16x8 v; };

__device__ __forceinline__ int cvtpk_bf16(float a, float b) {
  int r; asm("v_cvt_pk_bf16_f32 %0, %1, %2" : "=v"(r) : "v"(a), "v"(b)); return r;
}
__device__ __forceinline__ f32x4 mfma16(bf16x8 a, bf16x8 b, f32x4 c) {
  return __builtin_amdgcn_mfma_f32_16x16x32_bf16(a, b, c, 0, 0, 0);
}
__device__ __forceinline__ void gload16(const void* g, void* l) {
  __builtin_amdgcn_global_load_lds(
      (__attribute__((address_space(1))) void*)(g),
      (__attribute__((address_space(3))) void*)(l), 16, 0, 0);
}
__device__ __forceinline__ float bfu2f(uint32_t u) { return __uint_as_float(u << 16); }

// ---------------------------------------------------------------------------
// Prep kernel (r11-proven): gather (0..2047) + tile_pack_x (2048..3547)
// + tile_pack_w (3548..3803).
// ---------------------------------------------------------------------------
__global__ __launch_bounds__(256) void prep_kernel(
    const int* __restrict__ inputs, const int* __restrict__ shifts,
    const float* __restrict__ Wuf, const float* __restrict__ Wfu,
    const float* __restrict__ Wua, const float* __restrict__ Wau,
    const float* __restrict__ Wfe,
    const float* __restrict__ Wut, const float* __restrict__ Wuk1, const float* __restrict__ Wuk2,
    const float* __restrict__ Wft, const float* __restrict__ Wfk1, const float* __restrict__ Wfk2,
    const float* __restrict__ Wufd, const float* __restrict__ Wfud,
    const float* __restrict__ Wuad, const float* __restrict__ Waud,
    const float* __restrict__ W256, __hip_bfloat16* __restrict__ WtX,
    const float* __restrict__ W128, __hip_bfloat16* __restrict__ WtW,
    float* __restrict__ out)
{
  const int blk = blockIdx.x;
  const int t = threadIdx.x;

  if (blk < 2048) {                      // ---- gather ----
    const int b = blk;
    const int u = inputs[b*3 + 0];
    const int f = inputs[b*3 + 1];
    const int a = inputs[b*3 + 2];
    float* row = out + b * EXPERT_W;
    float* fm  = out + FM_BASE;

    for (int c = t; c < DD; c += 256) {
        float ufe = Wuf[u*DD + c];
        float uae = Wua[u*DD + c];
        float fue = Wfu[f*DD + c];
        float fee = Wfe[f*DD + c];
        float aue = Wau[a*DD + c];
        row[0    + c] = ufe;
        row[150  + c] = uae;
        row[620  + c] = fue;
        row[898  + c] = fee;
        row[1176 + c] = aue;
        fm[0*BB*DD + b*DD + c] = ufe;
        fm[1*BB*DD + b*DD + c] = uae;
        fm[2*BB*DD + b*DD + c] = fue;
        fm[3*BB*DD + b*DD + c] = aue;
    }
    for (int c = t; c < DKK; c += 256) {
        row[300  + c] = Wut [u*DKK + c];
        row[364  + c] = Wuk1[u*DKK + c];
        row[428  + c] = Wuk2[u*DKK + c];
        row[492  + c] = Wufd[u*DKK + c];
        row[556  + c] = Wuad[u*DKK + c];
        row[770  + c] = Wft [f*DKK + c];
        row[834  + c] = Wfk1[f*DKK + c];
        row[1048 + c] = Wfk2[f*DKK + c];
        row[1112 + c] = Wfud[f*DKK + c];
        row[1326 + c] = Waud[a*DKK + c];
    }
    if (t < 3) out[OH_BASE + b*3 + t] = (float)(inputs[b*3 + t] + shifts[t]);

  } else if (blk < 2048 + 1500) {        // ---- tile_pack_x ----
    const int T  = blk - 2048;
    const int jj = T / 300;
    const int i  = T - jj*300;
    float v[32];
    const float* src = W256 + ((size_t)i*150 + jj*32)*256 + t;
    #pragma unroll
    for (int jl = 0; jl < 32; ++jl) {
      int j = jj*32 + jl;
      v[jl] = (j < 150) ? src[(size_t)jl*256] : 0.f;
    }
    const int b16 = t >> 4, nloc = t & 15;
    char* dst = (char*)WtX + (size_t)T*16384 + (size_t)(b16*512 + nloc*8)*2;
    #pragma unroll
    for (int ksub = 0; ksub < 4; ++ksub) {
      int pk0 = cvtpk_bf16(v[ksub*8+0], v[ksub*8+1]);
      int pk1 = cvtpk_bf16(v[ksub*8+2], v[ksub*8+3]);
      int pk2 = cvtpk_bf16(v[ksub*8+4], v[ksub*8+5]);
      int pk3 = cvtpk_bf16(v[ksub*8+6], v[ksub*8+7]);
      *(int4*)(dst + (size_t)ksub*256) = make_int4(pk0, pk1, pk2, pk3);
    }

  } else {                               // ---- tile_pack_w ----
    if (t >= 128) return;
    const int T  = blk - 3548;
    const int jj = T >> 7;
    const int i  = T & 127;
    float v[32];
    const float* src = W128 + ((size_t)i*64 + jj*32)*128 + t;
    #pragma unroll
    for (int jl = 0; jl < 32; ++jl) v[jl] = src[(size_t)jl*128];
    const int b16 = t >> 4, nloc = t & 15;
    char* dst = (char*)WtW + (size_t)T*8192 + (size_t)(b16*512 + nloc*8)*2;
    #pragma unroll
    for (int ksub = 0; ksub < 4; ++ksub) {
      int pk0 = cvtpk_bf16(v[ksub*8+0], v[ksub*8+1]);
      int pk1 = cvtpk_bf16(v[ksub*8+2], v[ksub*8+3]);
      int pk2 = cvtpk_bf16(v[ksub*8+4], v[ksub*8+5]);
      int pk3 = cvtpk_bf16(v[ksub*8+6], v[ksub*8+7]);
      *(int4*)(dst + (size_t)ksub*256) = make_int4(pk0, pk1, pk2, pk3);
    }
  }
}

// ---------------------------------------------------------------------------
// xuser MFMA (r11 geometry — best measured: 66 us): 4-slot ring of 16 KB
// windows (2 cells each), ONE barrier per window, depth-3 window prefetch,
// counted vmcnt(4). grid 512 = 16mb x 16s x 2h; 8 waves (4mg x 2ng),
// wave = 2 mf x 4 nf. LDS 75.8 KB -> 2 blocks/CU.
// ---------------------------------------------------------------------------
__global__ __launch_bounds__(512, 4) void xuser_mfma(
    const int* __restrict__ inputs,
    const float* __restrict__ Wuf, const float* __restrict__ Wua,
    const float* __restrict__ Wfu, const float* __restrict__ Wau,
    const __hip_bfloat16* __restrict__ WtXt, __hip_bfloat16* __restrict__ wsX)
{
  __shared__ float xlds[128*20];                            // 10 KB
  __shared__ __align__(16) __hip_bfloat16 blds[4][8192];    // 4 x 16 KB ring

  const int bid = blockIdx.x;
  const int h  = bid & 1;
  const int s  = (bid >> 1) & 15;
  const int mb = bid >> 5;
  const int b0 = mb * 128;
  const bool upper = s >= 8;
  const int sl  = upper ? s - 8 : s;
  const int i0l = sl * 19;
  const int cnt = (150 - i0l) < 19 ? (150 - i0l) : 19;   // 19 or 17
  const int ig0 = i0l + (upper ? 150 : 0);
  const int tid = threadIdx.x;

  const float* X = upper ? Wua : Wuf;
  const float* Y = upper ? Wau : Wfu;
  const int yoff = upper ? 2 : 1;

  // stage x [128 rows][20 ii]
  for (int k = tid; k < 128*20; k += 512) {
    int r = k / 20, ii = k - r*20;
    float v = 0.f;
    if (ii < cnt) v = X[(size_t)inputs[(b0+r)*3]*150 + i0l + ii];
    xlds[k] = v;
  }

  const int lane = tid & 63;
  const int w  = tid >> 6;
  const int mg = w >> 1;        // 0..3 (32 rows each)
  const int ng = w & 1;         // 0..1 (64 cols each)
  const int lr = lane & 15;
  const int g  = lane >> 4;
  const unsigned wdst = (unsigned)(tid & ~63) * 16;   // wave-uniform LDS byte base

  int yid[2];
  #pragma unroll
  for (int mf = 0; mf < 2; ++mf)
    yid[mf] = inputs[(size_t)(b0 + mg*32 + mf*16 + lr)*3 + yoff];

  const char* wtb = (const char*)WtXt + (size_t)h*8192;

  // stage one window (2 cells) into slot; clamp past end (never consumed)
  int jjs = 0, iis = 0;
  auto stage2 = [&](int slot) {
    #pragma unroll
    for (int q = 0; q < 2; ++q) {
      const char* sp = wtb + (size_t)(jjs*300 + ig0 + iis)*16384 + (size_t)tid*16;
      gload16(sp, (char*)&blds[slot][q*4096] + wdst);
      if (iis + 1 < cnt) ++iis;
      else if (jjs + 1 < 5) { iis = 0; ++jjs; }
    }
  };

  f32x4 acc[2][4];
  #pragma unroll
  for (int i = 0; i < 2; ++i)
    #pragma unroll
    for (int j = 0; j < 4; ++j) acc[i][j] = (f32x4){0.f,0.f,0.f,0.f};

  const int P = 5 * cnt;          // cells (95 or 85)
  const int NW = (P + 1) >> 1;    // windows (48 or 43)

  stage2(0); stage2(1); stage2(2);      // prefetch depth 3

  int jjc = 0, iic = 0, pc = 0;   // consumption coords
  int yjj = -1;
  float yreg[2][8];

  for (int wi = 0; wi < NW; ++wi) {
    // wait for window wi's 2 loads; keep the 2 newest windows in flight
    const int ahead = NW - 1 - wi;
    if (ahead >= 2)      asm volatile("s_waitcnt vmcnt(4)" ::: "memory");
    else if (ahead == 1) asm volatile("s_waitcnt vmcnt(2)" ::: "memory");
    else                 asm volatile("s_waitcnt vmcnt(0)" ::: "memory");
    __builtin_amdgcn_s_barrier();

    if (wi + 3 < NW) stage2((wi + 3) & 3);      // issue early, fly under compute
    __builtin_amdgcn_sched_barrier(0);
    __builtin_amdgcn_s_setprio(1);

    const int slot = wi & 3;
    #pragma unroll
    for (int q = 0; q < 2; ++q) {
      if (pc >= P) break;
      if (jjc != yjj) {         // rebuild y fragments at jj stripe boundary
        yjj = jjc;
        const int jb = jjc*32 + g*8;
        #pragma unroll
        for (int mf = 0; mf < 2; ++mf) {
          const float* yp = Y + (size_t)yid[mf]*150;
          if (jb + 8 <= 150) {
            #pragma unroll
            for (int hh = 0; hh < 4; ++hh) {
              float2 vv = *(const float2*)(yp + jb + 2*hh);
              yreg[mf][2*hh]   = vv.x;
              yreg[mf][2*hh+1] = vv.y;
            }
          } else {
            #pragma unroll
            for (int e = 0; e < 8; ++e)
              yreg[mf][e] = (jb + e < 150) ? yp[jb + e] : 0.f;
          }
        }
      }
      const __hip_bfloat16* bb = &blds[slot][q*4096];
      bf16x8 bv[4];
      #pragma unroll
      for (int nf = 0; nf < 4; ++nf)
        bv[nf] = *(const bf16x8*)(bb + (ng*4 + nf)*512 + g*128 + lr*8);
      APack a[2];
      #pragma unroll
      for (int mf = 0; mf < 2; ++mf) {
        const float xv = xlds[(mg*32 + mf*16 + lr)*20 + iic];
        #pragma unroll
        for (int e = 0; e < 4; ++e)
          a[mf].d[e] = cvtpk_bf16(xv*yreg[mf][2*e], xv*yreg[mf][2*e+1]);
      }
      #pragma unroll
      for (int mf = 0; mf < 2; ++mf)
        #pragma unroll
        for (int nf = 0; nf < 4; ++nf)
          acc[mf][nf] = mfma16(a[mf].v, bv[nf], acc[mf][nf]);
      ++pc; ++iic; if (iic >= cnt) { iic = 0; ++jjc; }
    }
    __builtin_amdgcn_s_setprio(0);
  }

  // store bf16 partials: C/D layout: col = lane&15, row = 4*(lane>>4)+e
  __hip_bfloat16* wp = wsX + ((size_t)s*2048 + b0)*256;
  #pragma unroll
  for (int mf = 0; mf < 2; ++mf) {
    #pragma unroll
    for (int nf = 0; nf < 4; ++nf) {
      int rb  = mg*32 + mf*16 + g*4;
      int col = h*128 + ng*64 + nf*16 + lr;
      f32x4 v = acc[mf][nf];
      #pragma unroll
      for (int e = 0; e < 4; ++e)
        wp[(size_t)(rb+e)*256 + col] = __float2bfloat16(v[e]);
    }
  }
}

// ---------------------------------------------------------------------------
// wuser MFMA (proven): counted-vmcnt pipeline, bf16 partials.
// grid 256 = 16 mb x 16 s. 8 waves (4 mg x 2 ng); wave = 2 mf x 4 nf.
// ---------------------------------------------------------------------------
__global__ __launch_bounds__(512, 4) void wuser_mfma(
    const int* __restrict__ inputs,
    const float* __restrict__ Wufd, const float* __restrict__ Wuad,
    const float* __restrict__ Wfud, const float* __restrict__ Waud,
    const __hip_bfloat16* __restrict__ WtWt, __hip_bfloat16* __restrict__ wsW)
{
  __shared__ float xlds[128*8];                           // 4 KB
  __shared__ __align__(16) __hip_bfloat16 blds[2][8192];  // 2 x 16 KB

  const int mb = blockIdx.x >> 4;
  const int s  = blockIdx.x & 15;
  const int b0 = mb * 128;
  const bool upper = s >= 8;
  const int i0l = (s & 7) * 8;
  const int ig0 = i0l + (upper ? 64 : 0);
  const int tid = threadIdx.x;

  const float* X = upper ? Wuad : Wufd;
  const float* Y = upper ? Waud : Wfud;
  const int yoff = upper ? 2 : 1;

  for (int k = tid; k < 128*8; k += 512) {
    int r = k >> 3, ii = k & 7;
    xlds[k] = X[(size_t)inputs[(size_t)(b0+r)*3]*64 + i0l + ii];
  }

  const int lane = tid & 63;
  const int w  = tid >> 6;
  const int mg = w >> 1;
  const int ng = w & 1;
  const int lr = lane & 15;
  const int g  = lane >> 4;
  const unsigned wdst = (unsigned)(tid & ~63) * 16;

  int yid[2];
  #pragma unroll
  for (int mf = 0; mf < 2; ++mf)
    yid[mf] = inputs[(size_t)(b0 + mg*32 + mf*16 + lr)*3 + yoff];

  const char* wtb = (const char*)WtWt;

  auto stageT = [&](int bufi, int T) {
    const char* sp = wtb + (size_t)T*8192 + (size_t)tid*16;
    char* dp = (char*)&blds[bufi][0] + wdst;
    gload16(sp,        dp);
    gload16(sp + 8192, dp + 8192);
  };

  f32x4 acc[2][4];
  #pragma unroll
  for (int i = 0; i < 2; ++i)
    #pragma unroll
    for (int j = 0; j < 4; ++j) acc[i][j] = (f32x4){0.f,0.f,0.f,0.f};

  stageT(0, ig0);
  stageT(1, ig0 + 2);

  int jjc = 0, iic = 0;
  int jjs = 0, iis = 4;
  int yjj = -1;
  float yreg[2][8];

  for (int p = 0; p < 8; ++p) {
    if (jjc != yjj) {
      yjj = jjc;
      const int jb = jjc*32 + g*8;
      #pragma unroll
      for (int mf = 0; mf < 2; ++mf) {
        const float* yp = Y + (size_t)yid[mf]*64 + jb;
        #pragma unroll
        for (int hh = 0; hh < 2; ++hh) {
          float4 v = *(const float4*)(yp + hh*4);
          yreg[mf][hh*4]   = v.x;
          yreg[mf][hh*4+1] = v.y;
          yreg[mf][hh*4+2] = v.z;
          yreg[mf][hh*4+3] = v.w;
        }
      }
    }
    if (p + 1 < 8) asm volatile("s_waitcnt vmcnt(2)" ::: "memory");
    else           asm volatile("s_waitcnt vmcnt(0)" ::: "memory");
    __builtin_amdgcn_s_barrier();
    __builtin_amdgcn_sched_barrier(0);

    const int buf = p & 1;
    #pragma unroll
    for (int sc = 0; sc < 2; ++sc) {
      const __hip_bfloat16* bb = &blds[buf][sc*4096];
      bf16x8 bv[4];
      #pragma unroll
      for (int nf = 0; nf < 4; ++nf)
        bv[nf] = *(const bf16x8*)(bb + (ng*4 + nf)*512 + g*128 + lr*8);
      APack a[2];
      #pragma unroll
      for (int mf = 0; mf < 2; ++mf) {
        float xv = xlds[(mg*32 + mf*16 + lr)*8 + iic + sc];
        #pragma unroll
        for (int e = 0; e < 4; ++e)
          a[mf].d[e] = cvtpk_bf16(xv*yreg[mf][2*e], xv*yreg[mf][2*e+1]);
      }
      #pragma unroll
      for (int mf = 0; mf < 2; ++mf)
        #pragma unroll
        for (int nf = 0; nf < 4; ++nf)
          acc[mf][nf] = mfma16(a[mf].v, bv[nf], acc[mf][nf]);
    }

    __builtin_amdgcn_s_barrier();
    if (p + 2 < 8) stageT(buf, jjs*128 + ig0 + iis);

    iic += 2; if (iic >= 8) { iic = 0; ++jjc; }
    iis += 2; if (iis >= 8) { iis = 0; ++jjs; }
  }

  __hip_bfloat16* wp = wsW + ((size_t)s*2048 + b0)*128;
  #pragma unroll
  for (int mf = 0; mf < 2; ++mf) {
    #pragma unroll
    for (int nf = 0; nf < 4; ++nf) {
      int rb  = mg*32 + mf*16 + g*4;
      int col = ng*64 + nf*16 + lr;
      f32x4 v = acc[mf][nf];
      #pragma unroll
      for (int e = 0; e < 4; ++e)
        wp[(size_t)(rb+e)*128 + col] = __float2bfloat16(v[e]);
    }
  }
}

// ---------------------------------------------------------------------------
// Epilogue: sum bf16 partials + bias + relu (FIXED low-half decode, verified
// since r12's fix).
// ---------------------------------------------------------------------------
__global__ __launch_bounds__(256) void epilogue_kernel(
    const __hip_bfloat16* __restrict__ wsX, const __hip_bfloat16* __restrict__ wsW,
    const float* __restrict__ b256, const float* __restrict__ b128,
    float* __restrict__ out)
{
  int idx = blockIdx.x*256 + threadIdx.x;
  if (idx >= BB*192) return;
  int b = idx / 192, c2 = idx - b*192;
  if (c2 < 128) {
    int c = c2*2;
    float a0 = b256[c], a1 = b256[c+1];
    #pragma unroll
    for (int k = 0; k < 16; ++k) {
      uint32_t u = *(const uint32_t*)(wsX + ((size_t)k*BB + b)*256 + c);
      a0 += bfu2f(u);
      a1 += __uint_as_float(u & 0xffff0000u);
    }
    float2 r = make_float2(a0 > 0.f ? a0 : 0.f, a1 > 0.f ? a1 : 0.f);
    *(float2*)(out + (size_t)b*EXPERT_W + X_OFF + c) = r;
  } else {
    int cc = (c2 - 128)*2;
    float a0 = b128[cc], a1 = b128[cc+1];
    #pragma unroll
    for (int k = 0; k < 16; ++k) {
      uint32_t u = *(const uint32_t*)(wsW + ((size_t)k*BB + b)*128 + cc);
      a0 += bfu2f(u);
      a1 += __uint_as_float(u & 0xffff0000u);
    }
    float2 r = make_float2(a0 > 0.f ? a0 : 0.f, a1 > 0.f ? a1 : 0.f);
    *(float2*)(out + (size_t)b*EXPERT_W + W_OFF + cc) = r;
  }
}

// ---------------------------------------------------------------------------
// Fallback path (round-2, verified-passing) used if ws too small.
// ---------------------------------------------------------------------------
__global__ __launch_bounds__(256) void gather_kernel(
    const int* __restrict__ inputs, const int* __restrict__ shifts,
    const float* __restrict__ Wuf, const float* __restrict__ Wfu,
    const float* __restrict__ Wua, const float* __restrict__ Wau,
    const float* __restrict__ Wfe,
    const float* __restrict__ Wut, const float* __restrict__ Wuk1, const float* __restrict__ Wuk2,
    const float* __restrict__ Wft, const float* __restrict__ Wfk1, const float* __restrict__ Wfk2,
    const float* __restrict__ Wufd, const float* __restrict__ Wfud,
    const float* __restrict__ Wuad, const float* __restrict__ Waud,
    float* __restrict__ out)
{
    const int b = blockIdx.x;
    const int u = inputs[b*3 + 0];
    const int f = inputs[b*3 + 1];
    const int a = inputs[b*3 + 2];
    float* row = out + b * EXPERT_W;
    float* fm  = out + FM_BASE;
    const int t = threadIdx.x;

    for (int c = t; c < DD; c += 256) {
        float ufe = Wuf[u*DD + c];
        float uae = Wua[u*DD + c];
        float fue = Wfu[f*DD + c];
        float fee = Wfe[f*DD + c];
        float aue = Wau[a*DD + c];
        row[0    + c] = ufe;
        row[150  + c] = uae;
        row[620  + c] = fue;
        row[898  + c] = fee;
        row[1176 + c] = aue;
        fm[0*BB*DD + b*DD + c] = ufe;
        fm[1*BB*DD + b*DD + c] = uae;
        fm[2*BB*DD + b*DD + c] = fue;
        fm[3*BB*DD + b*DD + c] = aue;
    }
    for (int c = t; c < DKK; c += 256) {
        row[300  + c] = Wut [u*DKK + c];
        row[364  + c] = Wuk1[u*DKK + c];
        row[428  + c] = Wuk2[u*DKK + c];
        row[492  + c] = Wufd[u*DKK + c];
        row[556  + c] = Wuad[u*DKK + c];
        row[770  + c] = Wft [f*DKK + c];
        row[834  + c] = Wfk1[f*DKK + c];
        row[1048 + c] = Wfk2[f*DKK + c];
        row[1112 + c] = Wfud[f*DKK + c];
        row[1326 + c] = Waud[a*DKK + c];
    }
    if (t < 3) {
        out[OH_BASE + b*3 + t] = (float)(inputs[b*3 + t] + shifts[t]);
    }
}

static constexpr int NPAIR_X = 300 * 150;
static constexpr int CHX     = 128;

__global__ __launch_bounds__(256) void xuser_kernel(
    const int* __restrict__ inputs,
    const float* __restrict__ Wuf, const float* __restrict__ Wua,
    const float* __restrict__ Wfu, const float* __restrict__ Wau,
    const float* __restrict__ W256, const float* __restrict__ b256,
    float* __restrict__ out)
{
    __shared__ float xs[16][308];
    __shared__ float ys[16][308];
    __shared__ float xy[CHX][16];
    const int half = blockIdx.x & 1;
    const int bg   = blockIdx.x >> 1;
    const int b0   = bg * 16;
    const int t    = threadIdx.x;
    const int bl   = t & 15;
    const int kg   = t >> 4;
    const int kbase = half * 128 + kg * 8;
    for (int idx = t; idx < 16 * DD; idx += 256) {
        int bb = idx / DD;
        int c  = idx - bb * DD;
        int u = inputs[(b0+bb)*3 + 0];
        int f = inputs[(b0+bb)*3 + 1];
        int a = inputs[(b0+bb)*3 + 2];
        xs[bb][c]       = Wuf[u*DD + c];
        xs[bb][150 + c] = Wua[u*DD + c];
        ys[bb][c]       = Wfu[f*DD + c];
        ys[bb][150 + c] = Wau[a*DD + c];
    }
    float acc[8] = {0,0,0,0,0,0,0,0};
    for (int base = 0; base < NPAIR_X; base += CHX) {
        __syncthreads();
        #pragma unroll
        for (int r = 0; r < (CHX*16)/256; ++r) {
            int idx = t + r * 256;
            int pl  = idx >> 4;
            int bb  = idx & 15;
            int p   = base + pl;
            if (p < NPAIR_X) {
                int i = p / 150;
                int j = p - i * 150;
                xy[pl][bb] = xs[bb][i] * ys[bb][(i >= 150 ? 150 : 0) + j];
            }
        }
        __syncthreads();
        const int lim = min(CHX, NPAIR_X - base);
        const float* wp = W256 + base * 256 + kbase;
        for (int pl = 0; pl < lim; ++pl) {
            float sv = xy[pl][bl];
            const float4* w4 = (const float4*)(wp + pl * 256);
            float4 w0 = w4[0], w1 = w4[1];
            acc[0] = fmaf(sv, w0.x, acc[0]); acc[1] = fmaf(sv, w0.y, acc[1]);
            acc[2] = fmaf(sv, w0.z, acc[2]); acc[3] = fmaf(sv, w0.w, acc[3]);
            acc[4] = fmaf(sv, w1.x, acc[4]); acc[5] = fmaf(sv, w1.y, acc[5]);
            acc[6] = fmaf(sv, w1.z, acc[6]); acc[7] = fmaf(sv, w1.w, acc[7]);
        }
    }
    const int rowbase = (b0 + bl) * EXPERT_W + X_OFF;
    #pragma unroll
    for (int m = 0; m < 8; ++m) {
        float v = acc[m] + b256[kbase + m];
        out[rowbase + kbase + m] = (v > 0.f ? v : 0.f);
    }
}

static constexpr int NPAIR_W = 128 * 64;
static constexpr int CHW     = 256;

__global__ __launch_bounds__(256) void wuser_kernel(
    const int* __restrict__ inputs,
    const float* __restrict__ Wufd, const float* __restrict__ Wuad,
    const float* __restrict__ Wfud, const float* __restrict__ Waud,
    const float* __restrict__ W128, const float* __restrict__ b128,
    float* __restrict__ out)
{
    __shared__ float xs[8][132];
    __shared__ float ys[8][132];
    __shared__ float xy[CHW][8];
    const int bg = blockIdx.x;
    const int b0 = bg * 8;
    const int t  = threadIdx.x;
    const int bl = t & 7;
    const int kg = t >> 3;
    const int kbase = kg * 4;
    for (int idx = t; idx < 8 * DKK; idx += 256) {
        int bb = idx >> 6;
        int c  = idx & 63;
        int u = inputs[(b0+bb)*3 + 0];
        int f = inputs[(b0+bb)*3 + 1];
        int a = inputs[(b0+bb)*3 + 2];
        xs[bb][c]      = Wufd[u*DKK + c];
        xs[bb][64 + c] = Wuad[u*DKK + c];
        ys[bb][c]      = Wfud[f*DKK + c];
        ys[bb][64 + c] = Waud[a*DKK + c];
    }
    float acc[4] = {0,0,0,0};
    for (int base = 0; base < NPAIR_W; base += CHW) {
        __syncthreads();
        #pragma unroll
        for (int r = 0; r < (CHW*8)/256; ++r) {
            int idx = t + r * 256;
            int pl  = idx >> 3;
            int bb  = idx & 7;
            int p   = base + pl;
            int i = p >> 6;
            int j = p & 63;
            xy[pl][bb] = xs[bb][i] * ys[bb][(i >= 64 ? 64 : 0) + j];
        }
        __syncthreads();
        const float* wp = W128 + base * 128 + kbase;
        for (int pl = 0; pl < CHW; ++pl) {
            float sv = xy[pl][bl];
            float4 wv = *(const float4*)(wp + pl * 128);
            acc[0] = fmaf(sv, wv.x, acc[0]); acc[1] = fmaf(sv, wv.y, acc[1]);
            acc[2] = fmaf(sv, wv.z, acc[2]); acc[3] = fmaf(sv, wv.w, acc[3]);
        }
    }
    const int rowbase = (b0 + bl) * EXPERT_W + W_OFF;
    #pragma unroll
    for (int m = 0; m < 4; ++m) {
        float v = acc[m] + b128[kbase + m];
        out[rowbase + kbase + m] = (v > 0.f ? v : 0.f);
    }
}

// ---------------------------------------------------------------------------
extern "C" void kernel_launch(void* const* d_in, const int* in_sizes, int n_in,
                              void* d_out, int out_size, void* d_ws, size_t ws_size,
                              hipStream_t stream)
{
    const int*   inputs = (const int*)  d_in[0];
    const int*   shifts = (const int*)  d_in[1];
    const float* Wuf    = (const float*)d_in[2];
    const float* Wfu    = (const float*)d_in[3];
    const float* Wua    = (const float*)d_in[4];
    const float* Wau    = (const float*)d_in[5];
    const float* Wfe    = (const float*)d_in[6];
    const float* Wut    = (const float*)d_in[7];
    const float* Wuk1   = (const float*)d_in[8];
    const float* Wuk2   = (const float*)d_in[9];
    const float* Wft    = (const float*)d_in[10];
    const float* Wfk1   = (const float*)d_in[11];
    const float* Wfk2   = (const float*)d_in[12];
    const float* Wufd   = (const float*)d_in[13];
    const float* Wfud   = (const float*)d_in[14];
    const float* Wuad   = (const float*)d_in[15];
    const float* Waud   = (const float*)d_in[16];
    const float* W256   = (const float*)d_in[17];
    const float* b256   = (const float*)d_in[18];
    const float* W128   = (const float*)d_in[19];
    const float* b128   = (const float*)d_in[20];

    float* out = (float*)d_out;

    if (ws_size >= WS_NEED) {
        char* ws = (char*)d_ws;
        __hip_bfloat16* WtX = (__hip_bfloat16*)(ws + WTX_OFF);
        __hip_bfloat16* WtW = (__hip_bfloat16*)(ws + WTW_OFF);
        __hip_bfloat16* wsX = (__hip_bfloat16*)(ws + WSX_OFF);
        __hip_bfloat16* wsW = (__hip_bfloat16*)(ws + WSW_OFF);

        prep_kernel<<<3804, 256, 0, stream>>>(inputs, shifts,
            Wuf, Wfu, Wua, Wau, Wfe, Wut, Wuk1, Wuk2, Wft, Wfk1, Wfk2,
            Wufd, Wfud, Wuad, Waud, W256, WtX, W128, WtW, out);

        xuser_mfma<<<512, 512, 0, stream>>>(inputs, Wuf, Wua, Wfu, Wau, WtX, wsX);
        wuser_mfma<<<256, 512, 0, stream>>>(inputs, Wufd, Wuad, Wfud, Waud, WtW, wsW);

        epilogue_kernel<<<(BB*192 + 255)/256, 256, 0, stream>>>(wsX, wsW, b256, b128, out);
    } else {
        gather_kernel<<<BB, 256, 0, stream>>>(inputs, shifts,
            Wuf, Wfu, Wua, Wau, Wfe, Wut, Wuk1, Wuk2, Wft, Wfk1, Wfk2,
            Wufd, Wfud, Wuad, Waud, out);
        xuser_kernel<<<256, 256, 0, stream>>>(inputs, Wuf, Wua, Wfu, Wau, W256, b256, out);
        wuser_kernel<<<256, 256, 0, stream>>>(inputs, Wufd, Wuad, Wfud, Waud, W128, b128, out);
    }
}